// Round 16
// baseline (595.199 us; speedup 1.0000x reference)
//
#include <hip/hip_runtime.h>
#include <hip/hip_bf16.h>
#include <stdint.h>

typedef __attribute__((ext_vector_type(8))) short short8;
typedef __attribute__((ext_vector_type(8))) unsigned short ushort8;
typedef __attribute__((ext_vector_type(4))) float f32x4;
typedef __attribute__((ext_vector_type(8))) __bf16 bf16x8;

#define GAS __attribute__((address_space(1)))
#define LAS __attribute__((address_space(3)))

static constexpr int Bn = 16384;   // batch
static constexpr int Hn = 1024;    // hidden
static constexpr int KT = 4096;    // IN + H + CTX (concat K)
static constexpr int NT = KT / 64; // 64 K-tiles

#define SBAR()   __builtin_amdgcn_s_barrier()
#define VMCNT(n) asm volatile("s_waitcnt vmcnt(" #n ")" ::: "memory")
#define FENCE()  asm volatile("" ::: "memory")

__device__ __forceinline__ unsigned short f2bf(float f) {
  unsigned u = __builtin_bit_cast(unsigned, f);
  u = (u + 0x7FFFu + ((u >> 16) & 1u)) >> 16;   // RNE
  return (unsigned short)u;
}

__device__ __forceinline__ float fast_sigm(float x) {
  return __builtin_amdgcn_rcpf(1.f + __expf(-x));
}
__device__ __forceinline__ float fast_tanh(float x) {
  return 1.f - 2.f * __builtin_amdgcn_rcpf(__expf(2.f * x) + 1.f);
}

// Concat-convert 3 fp32 sources (widths 1024,1024,2048) into bf16 [rows][4096].
__global__ __launch_bounds__(256) void cvt_concat_k(
    const float* __restrict__ s0, const float* __restrict__ s1,
    const float* __restrict__ s2, unsigned short* __restrict__ dst,
    long long n8) {
  long long stride = (long long)gridDim.x * blockDim.x;
  for (long long g = (long long)blockIdx.x * blockDim.x + threadIdx.x; g < n8;
       g += stride) {
    long long row = g >> 9;
    int cg = (int)(g & 511) << 3;
    const float* src;
    if (cg < 1024)      src = s0 + row * 1024 + cg;
    else if (cg < 2048) src = s1 + row * 1024 + (cg - 1024);
    else                src = s2 + row * 2048 + (cg - 2048);
    float4 f0 = *(const float4*)src;
    float4 f1 = *(const float4*)(src + 4);
    ushort8 o;
    o[0] = f2bf(f0.x); o[1] = f2bf(f0.y); o[2] = f2bf(f0.z); o[3] = f2bf(f0.w);
    o[4] = f2bf(f1.x); o[5] = f2bf(f1.y); o[6] = f2bf(f1.z); o[7] = f2bf(f1.w);
    *(ushort8*)(dst + (g << 3)) = o;
  }
}

// Pack W|U|C into 16x16x32-MFMA B-frag records — WRITE-COALESCED (r10).
__global__ __launch_bounds__(256) void cvt_pack_w(
    const float* __restrict__ s0, const float* __restrict__ s1,
    const float* __restrict__ s2, unsigned short* __restrict__ dst,
    long long ntot) {
  long long stride = (long long)gridDim.x * blockDim.x;
  for (long long g = (long long)blockIdx.x * blockDim.x + threadIdx.x; g < ntot;
       g += stride) {
    int li = (int)(g & 63);
    long long rec = g >> 6;
    int cb = (int)(rec & 255);
    int k32 = (int)(rec >> 8);
    int fr = li & 15, ksl = li >> 4;
    int row = cb * 16 + fr;            // W-concat row = gemm column
    int k0 = k32 * 32 + ksl * 8;
    const float* src;
    if (k0 < 1024)      src = s0 + (size_t)row * 1024 + k0;
    else if (k0 < 2048) src = s1 + (size_t)row * 1024 + (k0 - 1024);
    else                src = s2 + (size_t)row * 2048 + (k0 - 2048);
    float4 f0 = *(const float4*)src;
    float4 f1 = *(const float4*)(src + 4);
    ushort8 o;
    o[0] = f2bf(f0.x); o[1] = f2bf(f0.y); o[2] = f2bf(f0.z); o[3] = f2bf(f0.w);
    o[4] = f2bf(f1.x); o[5] = f2bf(f1.y); o[6] = f2bf(f1.z); o[7] = f2bf(f1.w);
    *(ushort8*)(dst + (g << 3)) = o;
  }
}

// 256x256 GEMM + fused LSTM. 16x16x32 MFMA, 8 waves (2M x 4N).  [r10 core]
// r16 change: ONE-PHASE-AHEAD A register reads on the 1-barrier structure.
// r10's phases serialize {4 ds_read -> lgkm stall -> 16 MFMA} with both
// waves/SIMD in lockstep -> LDS pipe (1536 cyc/CU/tile) and MFMA pipe
// (2484 cyc/SIMD/tile) SUM. Fix: 4 rotating A buffers staged 3 tiles ahead;
// gate VMCNT(12) at tile top then retires A(t) AND A(t+1), so buf(t+1) is
// published by t's barrier -> q3 pre-reads t+1's q0 frags. areg[2][4]
// ping-pong by phase parity (static indices): every MFMA cluster consumes
// frags read one full phase earlier; reads issue under MFMAs.
// Ledger (12 VMEM/tile: B(t+1)x8 @q1, A(t+3)x4 @q3; in-order retirement):
//   top of t: newest 12 = tile t-1's issues -> retires A(t+1) (staged t-2)
//   and older. Overwrite at t targets buf (t+3)&3 = (t-1)&3, last read at
//   t-1 q2, fenced by t's barrier. Never vmcnt(0) mid-loop.
__global__ __launch_bounds__(512, 2) void lstm_gemm(
    const unsigned short* __restrict__ X, const unsigned short* __restrict__ Wp,
    const float* __restrict__ bias, const float* __restrict__ c0,
    float* __restrict__ out_c, float* __restrict__ out_h) {
  extern __shared__ char smem[];  // 4 x 32KB A buffers

  int bid = blockIdx.x;
  int swz = (bid & 7) * 128 + (bid >> 3);  // 1024 blocks, 8 XCDs, bijective
  int mblk = swz >> 4, cblk = swz & 15;    // 16 consecutive share A-panel
  int brow0 = mblk * 256;
  int hcol0 = cblk * 64;

  int tid = threadIdx.x;
  int lane = tid & 63, wid = tid >> 6;
  int wr = wid >> 2, wc = wid & 3;  // 2M x 4N wave grid

  const char* Xc = (const char*)X;
  const char* Wpc = (const char*)Wp;

  // ---- A staging: inverse-swizzled global source, linear LDS dest ----
  int rr = tid >> 3;                                        // 0..63
  uint32_t cbyte = (uint32_t)(((tid & 7) * 16) ^ ((rr & 7) << 4));
  uint32_t aoffj[4];
#pragma unroll
  for (int j = 0; j < 4; ++j)
    aoffj[j] = (uint32_t)(brow0 + j * 64 + rr) * (KT * 2) + cbyte;

  auto stage_A = [&](int tt) {             // 32KB = 4 x global_load_lds
    int ts = tt < NT ? tt : NT - 1;
    int dbuf = tt & 3;
#pragma unroll
    for (int j = 0; j < 4; ++j) {
      const char* src = Xc + aoffj[j] + (uint32_t)ts * 128u;
      char* dst = smem + dbuf * 32768 + j * 8192 + wid * 1024;
      __builtin_amdgcn_global_load_lds((const GAS unsigned int*)src,
                                       (LAS unsigned int*)dst, 16, 0, 0);
    }
  };

  // ---- A ds_read swizzled offsets ----
  int kg = (lane >> 4) << 4;
  int sw = (lane & 7) << 4;
  int koff0 = kg ^ sw;
  int koff1 = (64 + kg) ^ sw;
  int fr = lane & 15;

  // ---- B frag-major per-lane base pointers (gate n) ----
  const char* bbp[4];
#pragma unroll
  for (int n = 0; n < 4; ++n) {
    int cb = n * 64 + cblk * 4 + wc;
    bbp[n] = Wpc + ((size_t)cb * 64 + lane) * 16;
  }

  f32x4 acc[8][4] = {};
  short8 bfrE[4][2], bfrO[4][2];   // B frag parity sets [n][k-slice]
  short8 areg[2][4];               // [phase parity][a0k0,a0k1,a1k0,a1k1]

  // ---- prologue: A(0),A(1),A(2); B(0)->E   (20 VMEM, A(0) oldest) ----
  stage_A(0);
  stage_A(1);
  stage_A(2);
  FENCE();
#pragma unroll
  for (int n = 0; n < 4; ++n) {
    bfrE[n][0] = *(const short8*)(bbp[n]);
    bfrE[n][1] = *(const short8*)(bbp[n] + 262144);
  }
  VMCNT(16);   // retire A(0); keep A(1),A(2),B(0) in flight
  SBAR();
  {  // pre-read tile-0 q0 frags -> areg[0]
    int ab = (wr * 32 + fr) * 128;
    areg[0][0] = *(const short8*)(smem + ab + koff0);
    areg[0][1] = *(const short8*)(smem + ab + koff1);
    areg[0][2] = *(const short8*)(smem + ab + 2048 + koff0);
    areg[0][3] = *(const short8*)(smem + ab + 2048 + koff1);
  }

#define TILE(T_, BC, BN)                                                      \
  {                                                                           \
    VMCNT(12);                                                                \
    SBAR();                                                                   \
    int pb = ((T_) & 3) * 32768;                                              \
    int nb = (((T_) + 1) & 3) * 32768;                                        \
    _Pragma("unroll")                                                         \
    for (int q = 0; q < 4; ++q) {                                             \
      /* one-phase-ahead A reads: q<3 -> phase q+1 of this tile;             */\
      /* q==3 -> q0 of tile T_+1 (buf published by this tile's barrier)      */\
      if (q < 3) {                                                            \
        int ab = pb + ((2 * (q + 1) + wr) * 32 + fr) * 128;                   \
        areg[(q + 1) & 1][0] = *(const short8*)(smem + ab + koff0);           \
        areg[(q + 1) & 1][1] = *(const short8*)(smem + ab + koff1);           \
        areg[(q + 1) & 1][2] = *(const short8*)(smem + ab + 2048 + koff0);    \
        areg[(q + 1) & 1][3] = *(const short8*)(smem + ab + 2048 + koff1);    \
      } else {                                                                \
        int ab = nb + (wr * 32 + fr) * 128;                                   \
        areg[0][0] = *(const short8*)(smem + ab + koff0);                     \
        areg[0][1] = *(const short8*)(smem + ab + koff1);                     \
        areg[0][2] = *(const short8*)(smem + ab + 2048 + koff0);              \
        areg[0][3] = *(const short8*)(smem + ab + 2048 + koff1);              \
      }                                                                       \
      if (q == 1) {  /* coalesced B prefetch for T_+1, other parity */        \
        int ts = (T_) + 1 < NT ? (T_) + 1 : NT - 1;                           \
        size_t tb = (size_t)(2 * ts) * 262144u;                               \
        _Pragma("unroll")                                                     \
        for (int n = 0; n < 4; ++n) {                                         \
          BN[n][0] = *(const short8*)(bbp[n] + tb);                           \
          BN[n][1] = *(const short8*)(bbp[n] + tb + 262144);                  \
        }                                                                     \
      }                                                                       \
      if (q == 3) stage_A((T_) + 3);                                          \
      __builtin_amdgcn_s_setprio(1);                                          \
      _Pragma("unroll")                                                       \
      for (int n = 0; n < 4; ++n) {                                           \
        acc[2 * q][n] = __builtin_amdgcn_mfma_f32_16x16x32_bf16(              \
            __builtin_bit_cast(bf16x8, areg[q & 1][0]),                       \
            __builtin_bit_cast(bf16x8, BC[n][0]), acc[2 * q][n], 0, 0, 0);    \
        acc[2 * q + 1][n] = __builtin_amdgcn_mfma_f32_16x16x32_bf16(          \
            __builtin_bit_cast(bf16x8, areg[q & 1][2]),                       \
            __builtin_bit_cast(bf16x8, BC[n][0]), acc[2 * q + 1][n], 0, 0, 0);\
      }                                                                       \
      _Pragma("unroll")                                                       \
      for (int n = 0; n < 4; ++n) {                                           \
        acc[2 * q][n] = __builtin_amdgcn_mfma_f32_16x16x32_bf16(              \
            __builtin_bit_cast(bf16x8, areg[q & 1][1]),                       \
            __builtin_bit_cast(bf16x8, BC[n][1]), acc[2 * q][n], 0, 0, 0);    \
        acc[2 * q + 1][n] = __builtin_amdgcn_mfma_f32_16x16x32_bf16(          \
            __builtin_bit_cast(bf16x8, areg[q & 1][3]),                       \
            __builtin_bit_cast(bf16x8, BC[n][1]), acc[2 * q + 1][n], 0, 0, 0);\
      }                                                                       \
      __builtin_amdgcn_s_setprio(0);                                          \
    }                                                                         \
  }

  for (int t = 0; t < NT; t += 2) {
    TILE(t, bfrE, bfrO)
    TILE(t + 1, bfrO, bfrE)
  }
#undef TILE

  // ---- fused LSTM epilogue (acc[m][n]: n = gate) ----
  int col = hcol0 + wc * 16 + fr;
  float bi = bias[col], bf_ = bias[1024 + col];
  float bo = bias[2048 + col], bc = bias[3072 + col];
#pragma unroll
  for (int m = 0; m < 8; ++m) {
    int row0 = brow0 + (2 * (m >> 1) + wr) * 32 + (m & 1) * 16 + ((lane >> 4) << 2);
#pragma unroll
    for (int j = 0; j < 4; ++j) {
      size_t idx = (size_t)(row0 + j) * 1024 + col;
      float i_ = fast_sigm(acc[m][0][j] + bi);
      float f_ = fast_sigm(acc[m][1][j] + bf_);
      float o_ = fast_sigm(acc[m][2][j] + bo);
      float ch = fast_tanh(acc[m][3][j] + bc);
      float cn = i_ * ch + f_ * c0[idx];
      out_c[idx] = cn;
      out_h[idx] = o_ * fast_tanh(cn);
    }
  }
}

// Fallback if ws too small (not expected; ws >= 160MB confirmed in round 1).
__global__ __launch_bounds__(256) void lstm_naive(
    const float* __restrict__ y, const float* __restrict__ ctx,
    const float* __restrict__ c0, const float* __restrict__ h0,
    const float* __restrict__ W, const float* __restrict__ U,
    const float* __restrict__ C, const float* __restrict__ b,
    float* __restrict__ out_c, float* __restrict__ out_h) {
  size_t t = (size_t)blockIdx.x * blockDim.x + threadIdx.x;
  if (t >= (size_t)Bn * Hn) return;
  int row = (int)(t >> 10), col = (int)(t & 1023);
  float g[4];
#pragma unroll
  for (int gg = 0; gg < 4; ++gg) {
    int wrow = gg * 1024 + col;
    float s = b[wrow];
    const float* yr = y + (size_t)row * 1024;
    const float* Wr = W + (size_t)wrow * 1024;
    for (int k = 0; k < 1024; ++k) s += yr[k] * Wr[k];
    const float* hr = h0 + (size_t)row * 1024;
    const float* Ur = U + (size_t)wrow * 1024;
    for (int k = 0; k < 1024; ++k) s += hr[k] * Ur[k];
    const float* cr = ctx + (size_t)row * 2048;
    const float* Cr = C + (size_t)wrow * 2048;
    for (int k = 0; k < 2048; ++k) s += cr[k] * Cr[k];
    g[gg] = s;
  }
  float i_ = fast_sigm(g[0]), f_ = fast_sigm(g[1]);
  float o_ = fast_sigm(g[2]), ch = fast_tanh(g[3]);
  float cn = i_ * ch + f_ * c0[t];
  out_c[t] = cn;
  out_h[t] = o_ * fast_tanh(cn);
}

extern "C" void kernel_launch(void* const* d_in, const int* in_sizes, int n_in,
                              void* d_out, int out_size, void* d_ws, size_t ws_size,
                              hipStream_t stream) {
  const float* y   = (const float*)d_in[0];
  const float* ctx = (const float*)d_in[1];
  const float* c0  = (const float*)d_in[2];
  const float* h0  = (const float*)d_in[3];
  const float* W   = (const float*)d_in[4];
  const float* U   = (const float*)d_in[5];
  const float* C   = (const float*)d_in[6];
  const float* b   = (const float*)d_in[7];
  float* out = (float*)d_out;
  float* out_c = out;
  float* out_h = out + (size_t)Bn * Hn;

  const size_t needX = (size_t)Bn * KT * 2;
  const size_t needW = (size_t)(4 * Hn) * KT * 2;

  if (ws_size >= needX + needW) {
    unsigned short* Xb = (unsigned short*)d_ws;
    unsigned short* Wb = (unsigned short*)((char*)d_ws + needX);
    cvt_concat_k<<<2048, 256, 0, stream>>>(y, h0, ctx, Xb, (long long)Bn * 512);
    cvt_pack_w<<<2048, 256, 0, stream>>>(W, U, C, Wb,
                                         (long long)(4 * Hn) * KT / 8);
    (void)hipFuncSetAttribute((const void*)lstm_gemm,
                              hipFuncAttributeMaxDynamicSharedMemorySize, 131072);
    lstm_gemm<<<1024, 512, 131072, stream>>>(Xb, Wb, b, c0, out_c, out_h);
  } else {
    lstm_naive<<<(Bn * Hn + 255) / 256, 256, 0, stream>>>(y, ctx, c0, h0, W, U, C,
                                                          b, out_c, out_h);
  }
}

// Round 17
// 555.857 us; speedup vs baseline: 1.0708x; 1.0708x over previous
//
#include <hip/hip_runtime.h>
#include <hip/hip_bf16.h>
#include <stdint.h>

typedef __attribute__((ext_vector_type(8))) short short8;
typedef __attribute__((ext_vector_type(8))) unsigned short ushort8;
typedef __attribute__((ext_vector_type(4))) float f32x4;
typedef __attribute__((ext_vector_type(8))) __bf16 bf16x8;

#define GAS __attribute__((address_space(1)))
#define LAS __attribute__((address_space(3)))

static constexpr int Bn = 16384;   // batch
static constexpr int Hn = 1024;    // hidden
static constexpr int KT = 4096;    // IN + H + CTX (concat K)
static constexpr int NT = KT / 64; // 64 K-tiles per generation

#define SBAR()   __builtin_amdgcn_s_barrier()
#define VMCNT(n) asm volatile("s_waitcnt vmcnt(" #n ")" ::: "memory")
#define FENCE()  asm volatile("" ::: "memory")

__device__ __forceinline__ unsigned short f2bf(float f) {
  unsigned u = __builtin_bit_cast(unsigned, f);
  u = (u + 0x7FFFu + ((u >> 16) & 1u)) >> 16;   // RNE
  return (unsigned short)u;
}

__device__ __forceinline__ float fast_sigm(float x) {
  return __builtin_amdgcn_rcpf(1.f + __expf(-x));
}
__device__ __forceinline__ float fast_tanh(float x) {
  return 1.f - 2.f * __builtin_amdgcn_rcpf(__expf(2.f * x) + 1.f);
}

// Concat-convert 3 fp32 sources (widths 1024,1024,2048) into bf16 [rows][4096].
__global__ __launch_bounds__(256) void cvt_concat_k(
    const float* __restrict__ s0, const float* __restrict__ s1,
    const float* __restrict__ s2, unsigned short* __restrict__ dst,
    long long n8) {
  long long stride = (long long)gridDim.x * blockDim.x;
  for (long long g = (long long)blockIdx.x * blockDim.x + threadIdx.x; g < n8;
       g += stride) {
    long long row = g >> 9;
    int cg = (int)(g & 511) << 3;
    const float* src;
    if (cg < 1024)      src = s0 + row * 1024 + cg;
    else if (cg < 2048) src = s1 + row * 1024 + (cg - 1024);
    else                src = s2 + row * 2048 + (cg - 2048);
    float4 f0 = *(const float4*)src;
    float4 f1 = *(const float4*)(src + 4);
    ushort8 o;
    o[0] = f2bf(f0.x); o[1] = f2bf(f0.y); o[2] = f2bf(f0.z); o[3] = f2bf(f0.w);
    o[4] = f2bf(f1.x); o[5] = f2bf(f1.y); o[6] = f2bf(f1.z); o[7] = f2bf(f1.w);
    *(ushort8*)(dst + (g << 3)) = o;
  }
}

// Pack W|U|C into 16x16x32-MFMA B-frag records — WRITE-COALESCED (r10).
__global__ __launch_bounds__(256) void cvt_pack_w(
    const float* __restrict__ s0, const float* __restrict__ s1,
    const float* __restrict__ s2, unsigned short* __restrict__ dst,
    long long ntot) {
  long long stride = (long long)gridDim.x * blockDim.x;
  for (long long g = (long long)blockIdx.x * blockDim.x + threadIdx.x; g < ntot;
       g += stride) {
    int li = (int)(g & 63);
    long long rec = g >> 6;
    int cb = (int)(rec & 255);
    int k32 = (int)(rec >> 8);
    int fr = li & 15, ksl = li >> 4;
    int row = cb * 16 + fr;            // W-concat row = gemm column
    int k0 = k32 * 32 + ksl * 8;
    const float* src;
    if (k0 < 1024)      src = s0 + (size_t)row * 1024 + k0;
    else if (k0 < 2048) src = s1 + (size_t)row * 1024 + (k0 - 1024);
    else                src = s2 + (size_t)row * 2048 + (k0 - 2048);
    float4 f0 = *(const float4*)src;
    float4 f1 = *(const float4*)(src + 4);
    ushort8 o;
    o[0] = f2bf(f0.x); o[1] = f2bf(f0.y); o[2] = f2bf(f0.z); o[3] = f2bf(f0.w);
    o[4] = f2bf(f1.x); o[5] = f2bf(f1.y); o[6] = f2bf(f1.z); o[7] = f2bf(f1.w);
    *(ushort8*)(dst + (g << 3)) = o;
  }
}

// 256x256 GEMM + fused LSTM. 16x16x32 MFMA, 8 waves (2M x 4N).  [r10 core]
// r17 change: PERSISTENT BLOCKS. grid=256 (1/CU); each block runs 4 M-tiles
// (generations) at the SAME cblk. The r10 K-loop is UNCHANGED per tile; the
// tail clamped stages of gen g become the REAL A(0),A(1) of gen g+1, and the
// t=63 B-prefetch naturally targets B(g+1, tile0) ((g*64+t+1)&63 == 0). The
// continuous mod-3 buffer rotation lines up exactly with steady state
// (A'(0) staged at t=62 lands in buf ((g+1)*64)%3 = next gen's tile-0 buf),
// so the pipeline never drains across generations: the epilogue's VALU +
// global traffic covers next-gen staging latency; next-gen tile0's
// VMCNT(12)+SBAR retires A'(0) (older than the epilogue's VMEM) -> gate
// correctness preserved. B panel (2MB/cblk) stays L2-hot across all 4 gens.
// Ledger within a generation: identical to r10 (12 VMEM/tile: B(t+1)x8 @q1,
// A(t+2)x4 @q3; ONE {VMCNT(12); s_barrier} per tile; never vmcnt(0)).
__global__ __launch_bounds__(512, 2) void lstm_gemm(
    const unsigned short* __restrict__ X, const unsigned short* __restrict__ Wp,
    const float* __restrict__ bias, const float* __restrict__ c0,
    float* __restrict__ out_c, float* __restrict__ out_h) {
  extern __shared__ char smem[];  // 3 x 32KB A buffers

  int bid = blockIdx.x;
  int swz = (bid & 7) * 32 + (bid >> 3);   // 256 blocks, 8 XCDs, bijective
  int cblk = swz >> 4;                     // 0..15 (64 H-cols each)
  int mgroup = swz & 15;                   // 0..15 (4 M-tiles each)
  int hcol0 = cblk * 64;

  int tid = threadIdx.x;
  int lane = tid & 63, wid = tid >> 6;
  int wr = wid >> 2, wc = wid & 3;  // 2M x 4N wave grid

  const char* Xc = (const char*)X;
  const char* Wpc = (const char*)Wp;

  // ---- A staging bases: current gen (aoffj) and next gen (aoffjN) ----
  int rr = tid >> 3;                                        // 0..63
  uint32_t cbyte = (uint32_t)(((tid & 7) * 16) ^ ((rr & 7) << 4));
  uint32_t aoffj[4], aoffjN[4];
#pragma unroll
  for (int j = 0; j < 4; ++j) {
    aoffj[j] = (uint32_t)(mgroup * 1024 + j * 64 + rr) * 8192u + cbyte;
    aoffjN[j] = aoffj[j] + (256u * 8192u);   // +1 generation (256 rows)
  }

  // stage A K-tile ts (0..63) of current (nxt=0) or next (nxt=1) generation
  auto stage_A = [&](int ts, int nxt, int dbuf) {
#pragma unroll
    for (int j = 0; j < 4; ++j) {
      uint32_t off = (nxt ? aoffjN[j] : aoffj[j]) + (uint32_t)ts * 128u;
      const char* src = Xc + off;
      char* dst = smem + dbuf * 32768 + j * 8192 + wid * 1024;
      __builtin_amdgcn_global_load_lds((const GAS unsigned int*)src,
                                       (LAS unsigned int*)dst, 16, 0, 0);
    }
  };

  // ---- A ds_read swizzled offsets ----
  int kg = (lane >> 4) << 4;
  int sw = (lane & 7) << 4;
  int koff0 = kg ^ sw;
  int koff1 = (64 + kg) ^ sw;
  int fr = lane & 15;

  // ---- B frag-major per-lane base pointers (gate n) — cblk-only, all gens --
  const char* bbp[4];
#pragma unroll
  for (int n = 0; n < 4; ++n) {
    int cb = n * 64 + cblk * 4 + wc;
    bbp[n] = Wpc + ((size_t)cb * 64 + lane) * 16;
  }

  f32x4 acc[8][4] = {};
  short8 bfrE[4][2], bfrO[4][2];   // B frag parity sets [n][k-slice]

  // ---- prologue (once): A(g0,0); fence; B(0)->E + A(g0,1) ----
  stage_A(0, 0, 0);
  FENCE();
#pragma unroll
  for (int n = 0; n < 4; ++n) {
    bfrE[n][0] = *(const short8*)(bbp[n]);
    bfrE[n][1] = *(const short8*)(bbp[n] + 262144);
  }
  stage_A(1, 0, 1);

  int bufA = 0;

#define TILE(T_, G_, BC, BN)                                                  \
  {                                                                           \
    VMCNT(12);                                                                \
    SBAR();                                                                   \
    int pb = bufA * 32768;                                                    \
    int stg = bufA + 2; if (stg >= 3) stg -= 3;                               \
    _Pragma("unroll")                                                         \
    for (int q = 0; q < 4; ++q) {                                             \
      int ab = pb + ((2 * q + wr) * 32 + fr) * 128;                           \
      short8 a0 = *(const short8*)(smem + ab + koff0);                        \
      short8 a1 = *(const short8*)(smem + ab + koff1);                        \
      short8 a2 = *(const short8*)(smem + ab + 2048 + koff0);                 \
      short8 a3 = *(const short8*)(smem + ab + 2048 + koff1);                 \
      if (q == 1) {  /* coalesced B prefetch for global tile +1 */            \
        int gt1 = (G_)*NT + (T_) + 1;                                         \
        int tsb = gt1 < 4 * NT ? (gt1 & 63) : 63;                             \
        size_t tb = (size_t)(2 * tsb) * 262144u;                              \
        _Pragma("unroll")                                                     \
        for (int n = 0; n < 4; ++n) {                                         \
          BN[n][0] = *(const short8*)(bbp[n] + tb);                           \
          BN[n][1] = *(const short8*)(bbp[n] + tb + 262144);                  \
        }                                                                     \
      }                                                                       \
      if (q == 3) {  /* stage A tile +2 (rolls into next generation) */       \
        int tp2 = (T_) + 2;                                                   \
        stage_A(tp2 & 63, tp2 >= NT ? 1 : 0, stg);                            \
      }                                                                       \
      __builtin_amdgcn_s_setprio(1);                                          \
      _Pragma("unroll")                                                       \
      for (int n = 0; n < 4; ++n) {                                           \
        acc[2 * q][n] = __builtin_amdgcn_mfma_f32_16x16x32_bf16(              \
            __builtin_bit_cast(bf16x8, a0), __builtin_bit_cast(bf16x8, BC[n][0]),\
            acc[2 * q][n], 0, 0, 0);                                          \
        acc[2 * q + 1][n] = __builtin_amdgcn_mfma_f32_16x16x32_bf16(          \
            __builtin_bit_cast(bf16x8, a2), __builtin_bit_cast(bf16x8, BC[n][0]),\
            acc[2 * q + 1][n], 0, 0, 0);                                      \
      }                                                                       \
      _Pragma("unroll")                                                       \
      for (int n = 0; n < 4; ++n) {                                           \
        acc[2 * q][n] = __builtin_amdgcn_mfma_f32_16x16x32_bf16(              \
            __builtin_bit_cast(bf16x8, a1), __builtin_bit_cast(bf16x8, BC[n][1]),\
            acc[2 * q][n], 0, 0, 0);                                          \
        acc[2 * q + 1][n] = __builtin_amdgcn_mfma_f32_16x16x32_bf16(          \
            __builtin_bit_cast(bf16x8, a3), __builtin_bit_cast(bf16x8, BC[n][1]),\
            acc[2 * q + 1][n], 0, 0, 0);                                      \
      }                                                                       \
      __builtin_amdgcn_s_setprio(0);                                          \
    }                                                                         \
    bufA = bufA + 1; if (bufA >= 3) bufA = 0;                                 \
  }

  for (int g = 0; g < 4; ++g) {
    for (int t = 0; t < NT; t += 2) {
      TILE(t, g, bfrE, bfrO)
      TILE(t + 1, g, bfrO, bfrE)
    }

    // ---- fused LSTM epilogue for this generation (c0/out from global;
    //      next-gen A/B staging already in flight underneath) ----
    int brow0 = (mgroup * 4 + g) * 256;
    int col = hcol0 + wc * 16 + fr;
    float bi = bias[col], bf_ = bias[1024 + col];
    float bo = bias[2048 + col], bc = bias[3072 + col];
#pragma unroll
    for (int m = 0; m < 8; ++m) {
      int row0 =
          brow0 + (2 * (m >> 1) + wr) * 32 + (m & 1) * 16 + ((lane >> 4) << 2);
#pragma unroll
      for (int j = 0; j < 4; ++j) {
        size_t idx = (size_t)(row0 + j) * 1024 + col;
        float i_ = fast_sigm(acc[m][0][j] + bi);
        float f_ = fast_sigm(acc[m][1][j] + bf_);
        float o_ = fast_sigm(acc[m][2][j] + bo);
        float ch = fast_tanh(acc[m][3][j] + bc);
        float cn = i_ * ch + f_ * c0[idx];
        out_c[idx] = cn;
        out_h[idx] = o_ * fast_tanh(cn);
      }
    }

    // reset accumulators (element-wise: static indices, stays in AGPRs)
#pragma unroll
    for (int m = 0; m < 8; ++m)
#pragma unroll
      for (int n = 0; n < 4; ++n)
#pragma unroll
        for (int j = 0; j < 4; ++j) acc[m][n][j] = 0.f;

    // advance generation bases: aoffj <- aoffjN; aoffjN <- gen+2 (clamped)
#pragma unroll
    for (int j = 0; j < 4; ++j) {
      aoffj[j] = aoffjN[j];
      if (g < 2) aoffjN[j] += 256u * 8192u;
    }
  }
#undef TILE
}

// Fallback if ws too small (not expected; ws >= 160MB confirmed in round 1).
__global__ __launch_bounds__(256) void lstm_naive(
    const float* __restrict__ y, const float* __restrict__ ctx,
    const float* __restrict__ c0, const float* __restrict__ h0,
    const float* __restrict__ W, const float* __restrict__ U,
    const float* __restrict__ C, const float* __restrict__ b,
    float* __restrict__ out_c, float* __restrict__ out_h) {
  size_t t = (size_t)blockIdx.x * blockDim.x + threadIdx.x;
  if (t >= (size_t)Bn * Hn) return;
  int row = (int)(t >> 10), col = (int)(t & 1023);
  float g[4];
#pragma unroll
  for (int gg = 0; gg < 4; ++gg) {
    int wrow = gg * 1024 + col;
    float s = b[wrow];
    const float* yr = y + (size_t)row * 1024;
    const float* Wr = W + (size_t)wrow * 1024;
    for (int k = 0; k < 1024; ++k) s += yr[k] * Wr[k];
    const float* hr = h0 + (size_t)row * 1024;
    const float* Ur = U + (size_t)wrow * 1024;
    for (int k = 0; k < 1024; ++k) s += hr[k] * Ur[k];
    const float* cr = ctx + (size_t)row * 2048;
    const float* Cr = C + (size_t)wrow * 2048;
    for (int k = 0; k < 2048; ++k) s += cr[k] * Cr[k];
    g[gg] = s;
  }
  float i_ = fast_sigm(g[0]), f_ = fast_sigm(g[1]);
  float o_ = fast_sigm(g[2]), ch = fast_tanh(g[3]);
  float cn = i_ * ch + f_ * c0[t];
  out_c[t] = cn;
  out_h[t] = o_ * fast_tanh(cn);
}

extern "C" void kernel_launch(void* const* d_in, const int* in_sizes, int n_in,
                              void* d_out, int out_size, void* d_ws, size_t ws_size,
                              hipStream_t stream) {
  const float* y   = (const float*)d_in[0];
  const float* ctx = (const float*)d_in[1];
  const float* c0  = (const float*)d_in[2];
  const float* h0  = (const float*)d_in[3];
  const float* W   = (const float*)d_in[4];
  const float* U   = (const float*)d_in[5];
  const float* C   = (const float*)d_in[6];
  const float* b   = (const float*)d_in[7];
  float* out = (float*)d_out;
  float* out_c = out;
  float* out_h = out + (size_t)Bn * Hn;

  const size_t needX = (size_t)Bn * KT * 2;
  const size_t needW = (size_t)(4 * Hn) * KT * 2;

  if (ws_size >= needX + needW) {
    unsigned short* Xb = (unsigned short*)d_ws;
    unsigned short* Wb = (unsigned short*)((char*)d_ws + needX);
    cvt_concat_k<<<2048, 256, 0, stream>>>(y, h0, ctx, Xb, (long long)Bn * 512);
    cvt_pack_w<<<2048, 256, 0, stream>>>(W, U, C, Wb,
                                         (long long)(4 * Hn) * KT / 8);
    (void)hipFuncSetAttribute((const void*)lstm_gemm,
                              hipFuncAttributeMaxDynamicSharedMemorySize, 98304);
    lstm_gemm<<<256, 512, 98304, stream>>>(Xb, Wb, b, c0, out_c, out_h);
  } else {
    lstm_naive<<<(Bn * Hn + 255) / 256, 256, 0, stream>>>(y, ctx, c0, h0, W, U, C,
                                                          b, out_c, out_h);
  }
}